// Round 5
// baseline (514.772 us; speedup 1.0000x reference)
//
#include <hip/hip_runtime.h>
#include <hip/hip_bf16.h>

typedef __attribute__((ext_vector_type(4))) float floatx4;
typedef __attribute__((ext_vector_type(8))) __bf16 bf16x8;
typedef unsigned short ushort_t;

#define NENT  700
#define EMB   256
#define KDIM  1024
#define NDIM  512
#define HROWS 720   // 45*16: every row written by hab_kernel; reads stay <= 709
#define NPAIR 340000

// ws byte offsets — total ~7.4 MB
#define WS_HA   0
#define WS_HB   (WS_HA + HROWS*KDIM*2)
#define WS_W2H  (WS_HB + HROWS*KDIM*2)
#define WS_ENT  (WS_W2H + NDIM*KDIM*2)
#define WS_LG   (WS_ENT + NENT*EMB*4)

__device__ __forceinline__ float ldin(const void* p, int i, int isbf) {
    return isbf ? __bfloat162float(((const __hip_bfloat16*)p)[i])
                : ((const float*)p)[i];
}

// per-wave dtype sniff of entity_embedding; deterministic, no cross-kernel dep
__device__ __forceinline__ int detect_bf16(const ushort_t* __restrict__ w) {
    int t = threadIdx.x & 63;
    int e = (w[2*t] >> 7) & 0xFF;
    unsigned long long m = __ballot(e >= 100 && e <= 126);
    return (__popcll(m) >= 48) ? 1 : 0;   // bf16 ~64 hits, f32 ~7
}

// lgkmcnt(0) only; vmcnt untouched -> global prefetches survive the barrier
#define LDS_BARRIER() do { __builtin_amdgcn_s_waitcnt(0xC07F); __builtin_amdgcn_s_barrier(); } while (0)

// ---------------- stage 1: ent (88 blocks) + W2 repack (256 blocks), one launch ----------------
__global__ void entprep_kernel(const void* __restrict__ E, const void* __restrict__ Went,
                               const void* __restrict__ W2,
                               float* __restrict__ ent, __hip_bfloat16* __restrict__ W2H,
                               void* __restrict__ out) {
    int isbf = detect_bf16((const ushort_t*)E);
    if (blockIdx.x < 88) {
        int ib = blockIdx.x * 8, t = threadIdx.x;
        __shared__ float rows[8][EMB];
#pragma unroll
        for (int r = 0; r < 8; ++r) {
            int i = ib + r;
            rows[r][t] = (i < NENT) ? ldin(E, i*EMB + t, isbf) : 0.f;
        }
        __syncthreads();
        float acc[8] = {0.f,0.f,0.f,0.f,0.f,0.f,0.f,0.f};
        if (isbf) {
            const __hip_bfloat16* W = (const __hip_bfloat16*)Went;
            for (int k = 0; k < EMB; ++k) {
                float w = __bfloat162float(W[k*EMB + t]);
#pragma unroll
                for (int r = 0; r < 8; ++r) acc[r] += rows[r][k] * w;
            }
        } else {
            const float* W = (const float*)Went;
            for (int k = 0; k < EMB; ++k) {
                float w = W[k*EMB + t];
#pragma unroll
                for (int r = 0; r < 8; ++r) acc[r] += rows[r][k] * w;
            }
        }
#pragma unroll
        for (int r = 0; r < 8; ++r) {
            int i = ib + r;
            if (i < NENT) {
                ent[i*EMB + t] = acc[r];
                if (i < 200) {
                    if (isbf) ((__hip_bfloat16*)out)[680000 + i*EMB + t] = __float2bfloat16(acc[r]);
                    else      ((float*)out)[680000 + i*EMB + t] = acc[r];
                }
            }
        }
    } else {
        // W2H: elem ((half*32+kc)*16 + f)*512 + lane*8 + j
        //   = bf16(W2[(kc*32 + (lane>>4)*8 + j)*512 + half*256 + f*16 + (lane&15)])
        int g = (blockIdx.x - 88)*256 + threadIdx.x;     // 65536
        int lane = g & 63, f = (g >> 6) & 15, kc = (g >> 10) & 31, half = g >> 15;
        int l15 = lane & 15, quad = lane >> 4;
        int n = half*256 + f*16 + l15;
        bf16x8 v;
#pragma unroll
        for (int j = 0; j < 8; ++j) {
            int k = kc*32 + quad*8 + j;
            v[j] = (__bf16)ldin(W2, k*NDIM + n, isbf);
        }
        *(bf16x8*)(W2H + (size_t)g*8) = v;
    }
}

// ---------------- stage 2: HA/HB, 16 rows/block ----------------
__global__ void hab_kernel(const float* __restrict__ ent, const void* __restrict__ E,
                           const void* __restrict__ W1, const void* __restrict__ b1,
                           __hip_bfloat16* __restrict__ HA, __hip_bfloat16* __restrict__ HB) {
    int isbf = detect_bf16((const ushort_t*)E);
    int part = blockIdx.y;
    int ib = blockIdx.x * 16;
    int t = threadIdx.x;
    __shared__ float rows[16][EMB];
#pragma unroll
    for (int r = 0; r < 16; ++r) {
        int i = ib + r;
        rows[r][t] = (i < NENT) ? ent[i*EMB + t] : 0.f;
    }
    __syncthreads();
    float acc[16][4];
#pragma unroll
    for (int r = 0; r < 16; ++r)
#pragma unroll
        for (int p = 0; p < 4; ++p) acc[r][p] = 0.f;

    int wbase = part*EMB*KDIM;
    if (isbf) {
        const __hip_bfloat16* W = (const __hip_bfloat16*)W1;
        for (int k = 0; k < EMB; ++k) {
            float w[4];
#pragma unroll
            for (int p = 0; p < 4; ++p) w[p] = __bfloat162float(W[wbase + k*KDIM + t + p*256]);
#pragma unroll
            for (int r = 0; r < 16; ++r) {
                float e = rows[r][k];
#pragma unroll
                for (int p = 0; p < 4; ++p) acc[r][p] += e * w[p];
            }
        }
    } else {
        const float* W = (const float*)W1;
        for (int k = 0; k < EMB; ++k) {
            float w[4];
#pragma unroll
            for (int p = 0; p < 4; ++p) w[p] = W[wbase + k*KDIM + t + p*256];
#pragma unroll
            for (int r = 0; r < 16; ++r) {
                float e = rows[r][k];
#pragma unroll
                for (int p = 0; p < 4; ++p) acc[r][p] += e * w[p];
            }
        }
    }
    __hip_bfloat16* HX = part ? HB : HA;
#pragma unroll
    for (int r = 0; r < 16; ++r) {
#pragma unroll
        for (int p = 0; p < 4; ++p) {
            int n = t + p*256;
            float v = acc[r][p];
            if (!part) v += ldin(b1, n, isbf);
            HX[(ib + r)*KDIM + n] = __float2bfloat16(v);
        }
    }
}

union U8 { bf16x8 v; unsigned u[4]; };

// relu(ha + hb) -> bf16 round-half-up, pair-packed via v_perm
__device__ __forceinline__ bf16x8 mk_af3(bf16x8 ha, bf16x8 hb) {
    U8 r;
#pragma unroll
    for (int j = 0; j < 4; ++j) {
        float x0 = fmaxf((float)ha[2*j]   + (float)hb[2*j],   0.f);
        float x1 = fmaxf((float)ha[2*j+1] + (float)hb[2*j+1], 0.f);
        unsigned u0 = __float_as_uint(x0) + 0x8000u;
        unsigned u1 = __float_as_uint(x1) + 0x8000u;
#if defined(__has_builtin) && __has_builtin(__builtin_amdgcn_perm)
        r.u[j] = __builtin_amdgcn_perm(u1, u0, 0x07060302u);  // {u1.hi16, u0.hi16}
#else
        r.u[j] = (u0 >> 16) | (u1 & 0xFFFF0000u);
#endif
    }
    return r.v;
}

#define MFMA(a, b, c) __builtin_amdgcn_mfma_f32_16x16x32_bf16((a), (b), (c), 0, 0, 0)

// ---------------- main: fused pair MLP ----------------
// R17: R16 (M=128 tile) minus the register spill. R16 counters showed ~52 MB
// of scratch traffic (WRITE_SIZE 2.75->54 MB): acc=128 AGPR leaves 128 arch
// VGPRs, but unroll-hoisted a-frag ds_reads (64 regs) + B dbuf (64) + ha/hb
// (32) overflowed by ~12. Two cuts, reader side bit-identical:
//  (1) 3-reg rotation for the 8 a-frags per sub-phase (64 -> 24 regs).
//  (2) A-gen reassignment: wave w generates (m=2*(w>>1), kc=w&1) and
//      (m=2*(w>>1)+1, kc=w&1) — two i-rows at ONE k-chunk, so per-phase
//      operands are ha0+ha1+hb = 24 regs (was 32) and 3 loads (was 4).
__global__ __launch_bounds__(512, 2) void pair_kernel(
        const ushort_t* __restrict__ HA, const ushort_t* __restrict__ HB,
        const ushort_t* __restrict__ W2H, const void* __restrict__ E,
        const void* __restrict__ b2, const void* __restrict__ W3,
        const void* __restrict__ b3, void* __restrict__ out) {

    // per-type i-tiles = ceil(Na/8), j-tiles = ceil(Nb/16)
    const int blkEnd[10] = {325,650,900,1150,1400,1725,2050,2297,2544,2791};
    const int aB[10]  = {0,0,0,0,200,200,200,550,400,400};
    const int bB[10]  = {200,0,400,550,400,200,0,0,200,0};
    const int NaT[10] = {200,200,200,200,200,200,200,150,150,150};
    const int NbT[10] = {200,200,150,150,150,200,200,200,200,200};
    const int jTl[10] = {13,13,10,10,10,13,13,13,13,13};
    const int oOf[10] = {0,80000,160000,220000,280000,340000,420000,500000,560000,620000};

    __shared__ __align__(16) unsigned char sAF[32768];  // 2 phases x (2 kc x 8 m-frags x 1 KB)
    __shared__ float lgt[8][128][2];

    int bid = blockIdx.x;
    int ty = 0;
    while (bid >= blkEnd[ty]) ty++;
    int lb = bid - (ty ? blkEnd[ty-1] : 0);
    int jT = jTl[ty];
    int it = lb / jT;
    int jt = lb - it*jT;
    int i0 = aB[ty] + it*8;
    int j0 = bB[ty] + jt*16;

    int tid  = threadIdx.x;
    int lane = tid & 63;
    int w    = tid >> 6;       // 0..7: n64-slice it owns
    int kcw  = w & 1;          // kc slot this wave generates
    int mp   = (w >> 1) * 2;   // first of its two generated m-frags (i-rows)
    int l15  = lane & 15;
    int quad = lane >> 4;
    int kb   = (bid*7) & 31;   // per-block k-phase stagger

    // B frags: frag index = (w>>2)*512 + kc*16 + ((w&3)*4 + nf)  [unchanged layout]
    const char* WB = (const char*)W2H + ((size_t)((w>>2)*512 + (w&3)*4))*1024 + lane*16;
    const ushort_t* HBp  = HB + (j0 + l15)*KDIM + quad*8;
    const ushort_t* HAp0 = HA + (i0 + mp)*KDIM + quad*8;
    const ushort_t* HAp1 = HAp0 + KDIM;

    floatx4 acc[8][4];
#pragma unroll
    for (int mf = 0; mf < 8; ++mf)
#pragma unroll
        for (int nf = 0; nf < 4; ++nf) acc[mf][nf] = (floatx4){0.f,0.f,0.f,0.f};

    int k0 = kb, k1 = (kb + 1) & 31;
    bf16x8 Bc0 = *(const bf16x8*)(WB + (size_t)k0*16384);
    bf16x8 Bc1 = *(const bf16x8*)(WB + (size_t)k0*16384 + 1024);
    bf16x8 Bc2 = *(const bf16x8*)(WB + (size_t)k0*16384 + 2048);
    bf16x8 Bc3 = *(const bf16x8*)(WB + (size_t)k0*16384 + 3072);
    bf16x8 Bn0 = *(const bf16x8*)(WB + (size_t)k1*16384);
    bf16x8 Bn1 = *(const bf16x8*)(WB + (size_t)k1*16384 + 1024);
    bf16x8 Bn2 = *(const bf16x8*)(WB + (size_t)k1*16384 + 2048);
    bf16x8 Bn3 = *(const bf16x8*)(WB + (size_t)k1*16384 + 3072);

    // this wave's generated k-chunk for phase 0 (its kc slot only)
    int kg0 = (kb + kcw) & 31;
    bf16x8 ha0 = *(const bf16x8*)(HAp0 + kg0*32);
    bf16x8 ha1 = *(const bf16x8*)(HAp1 + kg0*32);
    bf16x8 hb  = *(const bf16x8*)(HBp + kg0*32);

#define MFMA4(mf, x, B0, B1, B2, B3)                         \
    acc[mf][0] = MFMA(x, B0, acc[mf][0]);                    \
    acc[mf][1] = MFMA(x, B1, acc[mf][1]);                    \
    acc[mf][2] = MFMA(x, B2, acc[mf][2]);                    \
    acc[mf][3] = MFMA(x, B3, acc[mf][3]);

#pragma unroll 2
    for (int ph = 0; ph < 16; ++ph) {
        // A-gen: frags (mp, kcw) and (mp+1, kcw) -> LDS
        char* sW = (char*)sAF + (ph & 1)*16384 + kcw*8192 + mp*1024 + lane*16;
        *(bf16x8*)(sW)        = mk_af3(ha0, hb);
        *(bf16x8*)(sW + 1024) = mk_af3(ha1, hb);
        // next-phase operand prefetch (wraps harmlessly at ph=15)
        int kgn = (kb + 2*(ph + 1) + kcw) & 31;
        ha0 = *(const bf16x8*)(HAp0 + kgn*32);
        ha1 = *(const bf16x8*)(HAp1 + kgn*32);
        hb  = *(const bf16x8*)(HBp + kgn*32);
        LDS_BARRIER();

        const char* sR = (const char*)sAF + (ph & 1)*16384 + lane*16;
        int kn2 = (kb + 2*ph + 2) & 31;
        int kn3 = (kb + 2*ph + 3) & 31;
        // sub 0 (kc0): 8 m-frags via 3-reg rotation (caps a-regs at 24)
        {
            bf16x8 x0 = *(const bf16x8*)(sR);
            bf16x8 x1 = *(const bf16x8*)(sR + 1024);
            bf16x8 x2 = *(const bf16x8*)(sR + 2048);
            MFMA4(0, x0, Bc0, Bc1, Bc2, Bc3); x0 = *(const bf16x8*)(sR + 3072);
            MFMA4(1, x1, Bc0, Bc1, Bc2, Bc3); x1 = *(const bf16x8*)(sR + 4096);
            MFMA4(2, x2, Bc0, Bc1, Bc2, Bc3); x2 = *(const bf16x8*)(sR + 5120);
            MFMA4(3, x0, Bc0, Bc1, Bc2, Bc3); x0 = *(const bf16x8*)(sR + 6144);
            MFMA4(4, x1, Bc0, Bc1, Bc2, Bc3); x1 = *(const bf16x8*)(sR + 7168);
            MFMA4(5, x2, Bc0, Bc1, Bc2, Bc3);
            MFMA4(6, x0, Bc0, Bc1, Bc2, Bc3);
            MFMA4(7, x1, Bc0, Bc1, Bc2, Bc3);
        }
        Bc0 = *(const bf16x8*)(WB + (size_t)kn2*16384);
        Bc1 = *(const bf16x8*)(WB + (size_t)kn2*16384 + 1024);
        Bc2 = *(const bf16x8*)(WB + (size_t)kn2*16384 + 2048);
        Bc3 = *(const bf16x8*)(WB + (size_t)kn2*16384 + 3072);
        // sub 1 (kc1)
        {
            bf16x8 x0 = *(const bf16x8*)(sR + 8192);
            bf16x8 x1 = *(const bf16x8*)(sR + 8192 + 1024);
            bf16x8 x2 = *(const bf16x8*)(sR + 8192 + 2048);
            MFMA4(0, x0, Bn0, Bn1, Bn2, Bn3); x0 = *(const bf16x8*)(sR + 8192 + 3072);
            MFMA4(1, x1, Bn0, Bn1, Bn2, Bn3); x1 = *(const bf16x8*)(sR + 8192 + 4096);
            MFMA4(2, x2, Bn0, Bn1, Bn2, Bn3); x2 = *(const bf16x8*)(sR + 8192 + 5120);
            MFMA4(3, x0, Bn0, Bn1, Bn2, Bn3); x0 = *(const bf16x8*)(sR + 8192 + 6144);
            MFMA4(4, x1, Bn0, Bn1, Bn2, Bn3); x1 = *(const bf16x8*)(sR + 8192 + 7168);
            MFMA4(5, x2, Bn0, Bn1, Bn2, Bn3);
            MFMA4(6, x0, Bn0, Bn1, Bn2, Bn3);
            MFMA4(7, x1, Bn0, Bn1, Bn2, Bn3);
        }
        Bn0 = *(const bf16x8*)(WB + (size_t)kn3*16384);
        Bn1 = *(const bf16x8*)(WB + (size_t)kn3*16384 + 1024);
        Bn2 = *(const bf16x8*)(WB + (size_t)kn3*16384 + 2048);
        Bn3 = *(const bf16x8*)(WB + (size_t)kn3*16384 + 3072);
    }
#undef MFMA4

    // epilogue: h2 = relu(acc + b2); partial logits over this wave's n64; LDS reduce across 8 waves
    int isbf = detect_bf16((const ushort_t*)E);
    int nb = w*64;
    float b2v[4], wa[4], wb[4];
#pragma unroll
    for (int nf = 0; nf < 4; ++nf) {
        int n = nb + nf*16 + l15;
        b2v[nf] = ldin(b2, n, isbf);
        wa[nf]  = ldin(W3, 2*n, isbf);
        wb[nf]  = ldin(W3, 2*n+1, isbf);
    }
#pragma unroll
    for (int mf = 0; mf < 8; ++mf) {
        float s0[4] = {0.f,0.f,0.f,0.f};
        float s1[4] = {0.f,0.f,0.f,0.f};
#pragma unroll
        for (int nf = 0; nf < 4; ++nf) {
            floatx4 c = acc[mf][nf];
#pragma unroll
            for (int r = 0; r < 4; ++r) {
                float v = fmaxf(c[r] + b2v[nf], 0.f);
                s0[r] += v * wa[nf];
                s1[r] += v * wb[nf];
            }
        }
#pragma unroll
        for (int off = 1; off < 16; off <<= 1) {
#pragma unroll
            for (int r = 0; r < 4; ++r) {
                s0[r] += __shfl_xor(s0[r], off, 64);
                s1[r] += __shfl_xor(s1[r], off, 64);
            }
        }
        if (l15 == 0) {
#pragma unroll
            for (int r = 0; r < 4; ++r) {
                int p = mf*16 + quad*4 + r;
                lgt[w][p][0] = s0[r];
                lgt[w][p][1] = s1[r];
            }
        }
    }
    __syncthreads();

    if (tid < 128) {
        int p = tid;
        float l0 = 0.f, l1 = 0.f;
#pragma unroll
        for (int ww = 0; ww < 8; ++ww) { l0 += lgt[ww][p][0]; l1 += lgt[ww][p][1]; }
        l0 += ldin(b3, 0, isbf);
        l1 += ldin(b3, 1, isbf);
        int pi = it*8 + (p >> 4), pj = jt*16 + (p & 15);
        if (pi < NaT[ty] && pj < NbT[ty]) {
            float mx = fmaxf(l0, l1);
            float e0 = __expf(l0 - mx), e1 = __expf(l1 - mx);
            float inv = 1.f / (e0 + e1);
            int o = oOf[ty] + (pi*NbT[ty] + pj)*2;
            if (isbf) {
                __hip_bfloat16* ob = (__hip_bfloat16*)out;
                ob[o]   = __float2bfloat16(e0 * inv);
                ob[o+1] = __float2bfloat16(e1 * inv);
            } else {
                float* of = (float*)out;
                of[o]   = e0 * inv;
                of[o+1] = e1 * inv;
            }
        }
    }
}

extern "C" void kernel_launch(void* const* d_in, const int* in_sizes, int n_in,
                              void* d_out, int out_size, void* d_ws, size_t ws_size,
                              hipStream_t stream) {
    const void* E    = d_in[1];
    const void* Went = d_in[3];
    const void* W1   = d_in[5];
    const void* b1   = d_in[6];
    const void* W2   = d_in[7];
    const void* b2   = d_in[8];
    const void* W3   = d_in[9];
    const void* b3   = d_in[10];

    char* ws = (char*)d_ws;
    __hip_bfloat16* HA   = (__hip_bfloat16*)(ws + WS_HA);
    __hip_bfloat16* HB   = (__hip_bfloat16*)(ws + WS_HB);
    __hip_bfloat16* W2H  = (__hip_bfloat16*)(ws + WS_W2H);
    float*          entf = (float*)(ws + WS_ENT);

    entprep_kernel<<<dim3(344), dim3(256), 0, stream>>>(E, Went, W2, entf, W2H, d_out);
    hab_kernel<<<dim3(45, 2), dim3(256), 0, stream>>>(entf, E, W1, b1, HA, HB);
    pair_kernel<<<dim3(2791), dim3(512), 0, stream>>>((const ushort_t*)HA, (const ushort_t*)HB,
                                                      (const ushort_t*)W2H, E, b2, W3, b3, d_out);
}

// Round 7
// 482.664 us; speedup vs baseline: 1.0665x; 1.0665x over previous
//
#include <hip/hip_runtime.h>
#include <hip/hip_bf16.h>

typedef __attribute__((ext_vector_type(4))) float floatx4;
typedef __attribute__((ext_vector_type(8))) __bf16 bf16x8;
typedef unsigned short ushort_t;

#define NENT  700
#define EMB   256
#define KDIM  1024
#define NDIM  512
#define HROWS 720   // 45*16: every row written by hab_kernel; reads stay <= 709
#define NPAIR 340000

// ws byte offsets — total ~7.4 MB
#define WS_HA   0
#define WS_HB   (WS_HA + HROWS*KDIM*2)
#define WS_W2H  (WS_HB + HROWS*KDIM*2)
#define WS_ENT  (WS_W2H + NDIM*KDIM*2)
#define WS_LG   (WS_ENT + NENT*EMB*4)

__device__ __forceinline__ float ldin(const void* p, int i, int isbf) {
    return isbf ? __bfloat162float(((const __hip_bfloat16*)p)[i])
                : ((const float*)p)[i];
}

// per-wave dtype sniff of entity_embedding; deterministic, no cross-kernel dep
__device__ __forceinline__ int detect_bf16(const ushort_t* __restrict__ w) {
    int t = threadIdx.x & 63;
    int e = (w[2*t] >> 7) & 0xFF;
    unsigned long long m = __ballot(e >= 100 && e <= 126);
    return (__popcll(m) >= 48) ? 1 : 0;   // bf16 ~64 hits, f32 ~7
}

// lgkmcnt(0) only; vmcnt untouched -> global prefetches survive the barrier
#define LDS_BARRIER() do { __builtin_amdgcn_s_waitcnt(0xC07F); __builtin_amdgcn_s_barrier(); } while (0)

// ---------------- stage 1: ent (88 blocks) + W2 repack (256 blocks), one launch ----------------
__global__ void entprep_kernel(const void* __restrict__ E, const void* __restrict__ Went,
                               const void* __restrict__ W2,
                               float* __restrict__ ent, __hip_bfloat16* __restrict__ W2H,
                               void* __restrict__ out) {
    int isbf = detect_bf16((const ushort_t*)E);
    if (blockIdx.x < 88) {
        int ib = blockIdx.x * 8, t = threadIdx.x;
        __shared__ float rows[8][EMB];
#pragma unroll
        for (int r = 0; r < 8; ++r) {
            int i = ib + r;
            rows[r][t] = (i < NENT) ? ldin(E, i*EMB + t, isbf) : 0.f;
        }
        __syncthreads();
        float acc[8] = {0.f,0.f,0.f,0.f,0.f,0.f,0.f,0.f};
        if (isbf) {
            const __hip_bfloat16* W = (const __hip_bfloat16*)Went;
            for (int k = 0; k < EMB; ++k) {
                float w = __bfloat162float(W[k*EMB + t]);
#pragma unroll
                for (int r = 0; r < 8; ++r) acc[r] += rows[r][k] * w;
            }
        } else {
            const float* W = (const float*)Went;
            for (int k = 0; k < EMB; ++k) {
                float w = W[k*EMB + t];
#pragma unroll
                for (int r = 0; r < 8; ++r) acc[r] += rows[r][k] * w;
            }
        }
#pragma unroll
        for (int r = 0; r < 8; ++r) {
            int i = ib + r;
            if (i < NENT) {
                ent[i*EMB + t] = acc[r];
                if (i < 200) {
                    if (isbf) ((__hip_bfloat16*)out)[680000 + i*EMB + t] = __float2bfloat16(acc[r]);
                    else      ((float*)out)[680000 + i*EMB + t] = acc[r];
                }
            }
        }
    } else {
        // W2H: elem ((half*32+kc)*16 + f)*512 + lane*8 + j
        //   = bf16(W2[(kc*32 + (lane>>4)*8 + j)*512 + half*256 + f*16 + (lane&15)])
        int g = (blockIdx.x - 88)*256 + threadIdx.x;     // 65536
        int lane = g & 63, f = (g >> 6) & 15, kc = (g >> 10) & 31, half = g >> 15;
        int l15 = lane & 15, quad = lane >> 4;
        int n = half*256 + f*16 + l15;
        bf16x8 v;
#pragma unroll
        for (int j = 0; j < 8; ++j) {
            int k = kc*32 + quad*8 + j;
            v[j] = (__bf16)ldin(W2, k*NDIM + n, isbf);
        }
        *(bf16x8*)(W2H + (size_t)g*8) = v;
    }
}

// ---------------- stage 2: HA/HB, 16 rows/block ----------------
__global__ void hab_kernel(const float* __restrict__ ent, const void* __restrict__ E,
                           const void* __restrict__ W1, const void* __restrict__ b1,
                           __hip_bfloat16* __restrict__ HA, __hip_bfloat16* __restrict__ HB) {
    int isbf = detect_bf16((const ushort_t*)E);
    int part = blockIdx.y;
    int ib = blockIdx.x * 16;
    int t = threadIdx.x;
    __shared__ float rows[16][EMB];
#pragma unroll
    for (int r = 0; r < 16; ++r) {
        int i = ib + r;
        rows[r][t] = (i < NENT) ? ent[i*EMB + t] : 0.f;
    }
    __syncthreads();
    float acc[16][4];
#pragma unroll
    for (int r = 0; r < 16; ++r)
#pragma unroll
        for (int p = 0; p < 4; ++p) acc[r][p] = 0.f;

    int wbase = part*EMB*KDIM;
    if (isbf) {
        const __hip_bfloat16* W = (const __hip_bfloat16*)W1;
        for (int k = 0; k < EMB; ++k) {
            float w[4];
#pragma unroll
            for (int p = 0; p < 4; ++p) w[p] = __bfloat162float(W[wbase + k*KDIM + t + p*256]);
#pragma unroll
            for (int r = 0; r < 16; ++r) {
                float e = rows[r][k];
#pragma unroll
                for (int p = 0; p < 4; ++p) acc[r][p] += e * w[p];
            }
        }
    } else {
        const float* W = (const float*)W1;
        for (int k = 0; k < EMB; ++k) {
            float w[4];
#pragma unroll
            for (int p = 0; p < 4; ++p) w[p] = W[wbase + k*KDIM + t + p*256];
#pragma unroll
            for (int r = 0; r < 16; ++r) {
                float e = rows[r][k];
#pragma unroll
                for (int p = 0; p < 4; ++p) acc[r][p] += e * w[p];
            }
        }
    }
    __hip_bfloat16* HX = part ? HB : HA;
#pragma unroll
    for (int r = 0; r < 16; ++r) {
#pragma unroll
        for (int p = 0; p < 4; ++p) {
            int n = t + p*256;
            float v = acc[r][p];
            if (!part) v += ldin(b1, n, isbf);
            HX[(ib + r)*KDIM + n] = __float2bfloat16(v);
        }
    }
}

union U8 { bf16x8 v; unsigned u[4]; };

// relu(ha + hb) -> bf16 round-half-up, pair-packed via v_perm
__device__ __forceinline__ bf16x8 mk_af3(bf16x8 ha, bf16x8 hb) {
    U8 r;
#pragma unroll
    for (int j = 0; j < 4; ++j) {
        float x0 = fmaxf((float)ha[2*j]   + (float)hb[2*j],   0.f);
        float x1 = fmaxf((float)ha[2*j+1] + (float)hb[2*j+1], 0.f);
        unsigned u0 = __float_as_uint(x0) + 0x8000u;
        unsigned u1 = __float_as_uint(x1) + 0x8000u;
#if defined(__has_builtin) && __has_builtin(__builtin_amdgcn_perm)
        r.u[j] = __builtin_amdgcn_perm(u1, u0, 0x07060302u);  // {u1.hi16, u0.hi16}
#else
        r.u[j] = (u0 >> 16) | (u1 & 0xFFFF0000u);
#endif
    }
    return r.v;
}

#define MFMA(a, b, c) __builtin_amdgcn_mfma_f32_16x16x32_bf16((a), (b), (c), 0, 0, 0)

// ---------------- main: fused pair MLP ----------------
// R19 == R18 resubmit (second container flake; kernel re-audited: bounds,
// barriers, LDS, reg budget all verified, no defect found).
// Two independent 4-wave blocks per CU (M=64 x N=512 each, wave owns
// N=128 = 8 n-frags across both W2 halves). vs R16 (one 8-wave M=128 block):
//  - LDS A-broadcast per CU-phase HALVES (each wave reads only its block's
//    M=64 tile: 8 waves x 8 KB = 64 KB vs 128 KB) — it was the in-phase BW floor.
//  - Independent barriers: block A's serial A-gen/barrier segment overlaps
//    block B's MFMAs (1 wave of each per SIMD).
//  - Honest reg budget: acc[4][8]=128 + B dbuf 64 + a 16 + ha/hb 12 + addr
//    ~16 = 236 < 256 @ 2 waves/SIMD; unroll 1 stops cross-phase doubling.
//  - No partial-logit combine: block owns whole pairs (R15 tables/epilogue).
// A-gen: wave w generates frags (m=(w>>1)*2+{0,1}, kc=w&1). Per-wave MFMA
// batch unchanged (64/phase).
__global__ __launch_bounds__(256, 2) void pair_kernel(
        const ushort_t* __restrict__ HA, const ushort_t* __restrict__ HB,
        const ushort_t* __restrict__ W2H, const void* __restrict__ E,
        const void* __restrict__ b2, const void* __restrict__ W3,
        const void* __restrict__ b3, void* __restrict__ out) {

    const int blkEnd[10] = {650,1300,1800,2300,2800,3450,4100,4594,5088,5582};
    const int aB[10]  = {0,0,0,0,200,200,200,550,400,400};
    const int bB[10]  = {200,0,400,550,400,200,0,0,200,0};
    const int NaT[10] = {200,200,200,200,200,200,200,150,150,150};
    const int NbT[10] = {200,200,150,150,150,200,200,200,200,200};
    const int jTl[10] = {13,13,10,10,10,13,13,13,13,13};
    const int oOf[10] = {0,80000,160000,220000,280000,340000,420000,500000,560000,620000};

    __shared__ __align__(16) unsigned char sAF[16384];  // 2 phases x (2 kc x 4 m-frags x 1 KB)
    __shared__ float lgt[4][64][2];

    int bid = blockIdx.x;
    int ty = 0;
    while (bid >= blkEnd[ty]) ty++;
    int lb = bid - (ty ? blkEnd[ty-1] : 0);
    int jT = jTl[ty];
    int it = lb / jT;
    int jt = lb - it*jT;
    int i0 = aB[ty] + it*4;
    int j0 = bB[ty] + jt*16;

    int tid  = threadIdx.x;
    int lane = tid & 63;
    int w    = tid >> 6;       // 0..3
    int kcw  = w & 1;          // kc slot this wave generates
    int mp   = (w >> 1) * 2;   // first of its two generated m-frags
    int l15  = lane & 15;
    int quad = lane >> 4;
    int kb   = (bid*7) & 31;   // per-block k-phase stagger

    // B frag byte addr = half*512KB + kc*16KB + f*1KB; wave reads f = w*4+nf of BOTH halves
    const char* WB0 = (const char*)W2H + (size_t)(w*4)*1024 + lane*16;
    const char* WB1 = WB0 + (size_t)512*1024;
    const ushort_t* HBp  = HB + (j0 + l15)*KDIM + quad*8;
    const ushort_t* HAp0 = HA + (i0 + mp)*KDIM + quad*8;
    const ushort_t* HAp1 = HAp0 + KDIM;

    floatx4 acc[4][8];
#pragma unroll
    for (int mf = 0; mf < 4; ++mf)
#pragma unroll
        for (int hf = 0; hf < 8; ++hf) acc[mf][hf] = (floatx4){0.f,0.f,0.f,0.f};

    bf16x8 Bc[2][4], Bn[2][4];
    int k0 = kb, k1 = (kb + 1) & 31;
#pragma unroll
    for (int nf = 0; nf < 4; ++nf) {
        Bc[0][nf] = *(const bf16x8*)(WB0 + (size_t)k0*16384 + nf*1024);
        Bc[1][nf] = *(const bf16x8*)(WB1 + (size_t)k0*16384 + nf*1024);
        Bn[0][nf] = *(const bf16x8*)(WB0 + (size_t)k1*16384 + nf*1024);
        Bn[1][nf] = *(const bf16x8*)(WB1 + (size_t)k1*16384 + nf*1024);
    }
    int kg0 = (kb + kcw) & 31;
    bf16x8 ha0 = *(const bf16x8*)(HAp0 + kg0*32);
    bf16x8 ha1 = *(const bf16x8*)(HAp1 + kg0*32);
    bf16x8 hb  = *(const bf16x8*)(HBp + kg0*32);

#pragma unroll 1
    for (int ph = 0; ph < 16; ++ph) {
        // A-gen: frags (mp,kcw),(mp+1,kcw) -> LDS slot kc*4KB + m*1KB
        char* sW = (char*)sAF + (ph & 1)*8192 + kcw*4096 + mp*1024 + lane*16;
        *(bf16x8*)(sW)        = mk_af3(ha0, hb);
        *(bf16x8*)(sW + 1024) = mk_af3(ha1, hb);
        // next-phase operand prefetch (wraps harmlessly at ph=15)
        int kgn = (kb + 2*ph + 2 + kcw) & 31;
        ha0 = *(const bf16x8*)(HAp0 + kgn*32);
        ha1 = *(const bf16x8*)(HAp1 + kgn*32);
        hb  = *(const bf16x8*)(HBp + kgn*32);
        LDS_BARRIER();

        const char* sR = (const char*)sAF + (ph & 1)*8192 + lane*16;
        int kn2 = (kb + 2*ph + 2) & 31;
        int kn3 = (kb + 2*ph + 3) & 31;
        // sub 0 (kc0): 4 m-frags x 8 (half,nf)
#pragma unroll
        for (int m = 0; m < 4; ++m) {
            bf16x8 a = *(const bf16x8*)(sR + m*1024);
#pragma unroll
            for (int hf = 0; hf < 8; ++hf)
                acc[m][hf] = MFMA(a, Bc[hf>>2][hf&3], acc[m][hf]);
        }
#pragma unroll
        for (int nf = 0; nf < 4; ++nf) {
            Bc[0][nf] = *(const bf16x8*)(WB0 + (size_t)kn2*16384 + nf*1024);
            Bc[1][nf] = *(const bf16x8*)(WB1 + (size_t)kn2*16384 + nf*1024);
        }
        // sub 1 (kc1)
#pragma unroll
        for (int m = 0; m < 4; ++m) {
            bf16x8 a = *(const bf16x8*)(sR + 4096 + m*1024);
#pragma unroll
            for (int hf = 0; hf < 8; ++hf)
                acc[m][hf] = MFMA(a, Bn[hf>>2][hf&3], acc[m][hf]);
        }
#pragma unroll
        for (int nf = 0; nf < 4; ++nf) {
            Bn[0][nf] = *(const bf16x8*)(WB0 + (size_t)kn3*16384 + nf*1024);
            Bn[1][nf] = *(const bf16x8*)(WB1 + (size_t)kn3*16384 + nf*1024);
        }
    }

    // epilogue: h2 = relu(acc + b2); partial logits over this wave's n128; LDS reduce across 4 waves
    int isbf = detect_bf16((const ushort_t*)E);
    float b2v[8], wa[8], wb[8];
#pragma unroll
    for (int hf = 0; hf < 8; ++hf) {
        int n = (hf >> 2)*256 + w*64 + (hf & 3)*16 + l15;
        b2v[hf] = ldin(b2, n, isbf);
        wa[hf]  = ldin(W3, 2*n, isbf);
        wb[hf]  = ldin(W3, 2*n+1, isbf);
    }
#pragma unroll
    for (int mf = 0; mf < 4; ++mf) {
        float s0[4] = {0.f,0.f,0.f,0.f};
        float s1[4] = {0.f,0.f,0.f,0.f};
#pragma unroll
        for (int hf = 0; hf < 8; ++hf) {
            floatx4 c = acc[mf][hf];
#pragma unroll
            for (int r = 0; r < 4; ++r) {
                float v = fmaxf(c[r] + b2v[hf], 0.f);
                s0[r] += v * wa[hf];
                s1[r] += v * wb[hf];
            }
        }
#pragma unroll
        for (int off = 1; off < 16; off <<= 1) {
#pragma unroll
            for (int r = 0; r < 4; ++r) {
                s0[r] += __shfl_xor(s0[r], off, 64);
                s1[r] += __shfl_xor(s1[r], off, 64);
            }
        }
        if (l15 == 0) {
#pragma unroll
            for (int r = 0; r < 4; ++r) {
                int p = mf*16 + quad*4 + r;
                lgt[w][p][0] = s0[r];
                lgt[w][p][1] = s1[r];
            }
        }
    }
    __syncthreads();

    if (tid < 64) {
        int p = tid;
        float l0 = lgt[0][p][0] + lgt[1][p][0] + lgt[2][p][0] + lgt[3][p][0];
        float l1 = lgt[0][p][1] + lgt[1][p][1] + lgt[2][p][1] + lgt[3][p][1];
        l0 += ldin(b3, 0, isbf);
        l1 += ldin(b3, 1, isbf);
        int pi = it*4 + (p >> 4), pj = jt*16 + (p & 15);
        if (pi < NaT[ty] && pj < NbT[ty]) {
            float mx = fmaxf(l0, l1);
            float e0 = __expf(l0 - mx), e1 = __expf(l1 - mx);
            float inv = 1.f / (e0 + e1);
            int o = oOf[ty] + (pi*NbT[ty] + pj)*2;
            if (isbf) {
                __hip_bfloat16* ob = (__hip_bfloat16*)out;
                ob[o]   = __float2bfloat16(e0 * inv);
                ob[o+1] = __float2bfloat16(e1 * inv);
            } else {
                float* of = (float*)out;
                of[o]   = e0 * inv;
                of[o+1] = e1 * inv;
            }
        }
    }
}

extern "C" void kernel_launch(void* const* d_in, const int* in_sizes, int n_in,
                              void* d_out, int out_size, void* d_ws, size_t ws_size,
                              hipStream_t stream) {
    const void* E    = d_in[1];
    const void* Went = d_in[3];
    const void* W1   = d_in[5];
    const void* b1   = d_in[6];
    const void* W2   = d_in[7];
    const void* b2   = d_in[8];
    const void* W3   = d_in[9];
    const void* b3   = d_in[10];

    char* ws = (char*)d_ws;
    __hip_bfloat16* HA   = (__hip_bfloat16*)(ws + WS_HA);
    __hip_bfloat16* HB   = (__hip_bfloat16*)(ws + WS_HB);
    __hip_bfloat16* W2H  = (__hip_bfloat16*)(ws + WS_W2H);
    float*          entf = (float*)(ws + WS_ENT);

    entprep_kernel<<<dim3(344), dim3(256), 0, stream>>>(E, Went, W2, entf, W2H, d_out);
    hab_kernel<<<dim3(45, 2), dim3(256), 0, stream>>>(entf, E, W1, b1, HA, HB);
    pair_kernel<<<dim3(5582), dim3(256), 0, stream>>>((const ushort_t*)HA, (const ushort_t*)HB,
                                                      (const ushort_t*)W2H, E, b2, W3, b3, d_out);
}